// Round 23
// baseline (2252.349 us; speedup 1.0000x reference)
//
#include <hip/hip_runtime.h>
#include <hip/hip_bf16.h>
#include <cstdint>
#include <cstddef>

#define HEADS 12
#define LL 3136
#define ROWS 100352   // 32*3136
#define SCALE 0.17677669529663687f

typedef __hip_bfloat16 bf16;
typedef __attribute__((ext_vector_type(8))) short short8;
typedef __attribute__((ext_vector_type(4))) short s4;
typedef __attribute__((ext_vector_type(4))) float f32x4;

__device__ __forceinline__ float bf2f(unsigned short u) {
  union { uint32_t u32; float f; } x; x.u32 = ((uint32_t)u) << 16; return x.f;
}
__device__ __forceinline__ unsigned short f2bf_bits(float f) {
  union { float f; uint32_t u; } x; x.f = f;
  uint32_t r = x.u + 0x7fffu + ((x.u >> 16) & 1u);
  return (unsigned short)(r >> 16);
}
// tanh-form GELU via hw exp; max |err| ~3e-4.
__device__ __forceinline__ float gelu_fast(float x) {
  float t2 = x * (1.5957691216f + 0.0713548162726f * x * x);
  float e = __expf(t2);
  return x * (e / (e + 1.0f));
}
// fragment-packed address for element (row, c) consumed as MFMA A-operand; nkf = K/32
__device__ __forceinline__ size_t frag_addr(int row, int c, int nkf) {
  return ((size_t)(row >> 4) * nkf + (c >> 5)) * 512
       + (size_t)(((row & 15) + (((c & 31) >> 3) << 4)) * 8 + (c & 7));
}

// ---------------- prep kernels ----------------
__global__ __launch_bounds__(64) void prep_fragB(const float* __restrict__ src,
    bf16* __restrict__ dst, int K, int N, int scaleLim, float scale) {
  const int nf = blockIdx.x, kf = blockIdx.y;
  const int l = threadIdx.x;
  const int n = nf * 16 + (l & 15);
  const int k0 = kf * 32 + (l >> 4) * 8;
  const float sc = (n < scaleLim) ? scale : 1.f;
  short8 v;
  #pragma unroll
  for (int j = 0; j < 8; ++j)
    v[j] = (short)f2bf_bits(src[(size_t)(k0 + j) * N + n] * sc);
  *(short8*)&dst[(((size_t)nf * (K >> 5) + kf) * 64 + l) * 8] = v;
}

__global__ void prep_qb(const float* __restrict__ qkv_b, float* __restrict__ qb) {
  int idx = blockIdx.x * 256 + threadIdx.x;
  if (idx < 1152) qb[idx] = qkv_b[idx] * (idx < 384 ? SCALE : 1.0f);
}

__global__ void prep_biasM(const float* __restrict__ rpb, const int* __restrict__ rel,
                           f32x4* __restrict__ biasM) {
  int h = blockIdx.x;
  int t = blockIdx.y;
  int mi = t >> 2, ni = t & 3;
  int lane = threadIdx.x;
  int q = ni * 16 + (lane & 15);
  int g = lane >> 4;
  f32x4 v;
  #pragma unroll
  for (int j = 0; j < 4; ++j) {
    int k = mi * 16 + g * 4 + j;
    float b;
    if (k < 49) b = (q < 49) ? rpb[rel[q * 49 + k] * HEADS + h] : 0.f;
    else        b = -1e30f;
    v[j] = b;
  }
  biasM[((h * 4 + mi) * 4 + ni) * 64 + lane] = v;
}

// ---------------- LayerNorm; FRAGOUT writes MFMA-A-fragment order (nkf=12) ------
template<bool WIN, bool BF16IN, bool FRAGOUT>
__global__ __launch_bounds__(256) void ln_kernel(const float* __restrict__ xf,
    const bf16* __restrict__ xb, const float* __restrict__ g,
    const float* __restrict__ b, bf16* __restrict__ out) {
  int row = blockIdx.x * 4 + (threadIdx.x >> 6);
  int lane = threadIdx.x & 63;
  size_t src;
  if (WIN) {
    int w = row / 49, p = row - w * 49;
    int bb = w >> 6, wy = (w >> 3) & 7, wx = w & 7;
    int iy = p / 7, ix = p - iy * 7;
    int l = (wy * 7 + iy) * 56 + wx * 7 + ix;
    src = ((size_t)bb * LL + l) * 384;
  } else {
    src = (size_t)row * 384;
  }
  float vals[6];
  float s = 0.f, s2 = 0.f;
  #pragma unroll
  for (int j = 0; j < 6; ++j) {
    float v = BF16IN ? bf2f(*(const unsigned short*)&xb[src + lane + 64 * j])
                     : xf[src + lane + 64 * j];
    vals[j] = v; s += v; s2 += v * v;
  }
  #pragma unroll
  for (int off = 32; off >= 1; off >>= 1) {
    s  += __shfl_xor(s, off);
    s2 += __shfl_xor(s2, off);
  }
  float m  = s * (1.f / 384.f);
  float var = s2 * (1.f / 384.f) - m * m;
  float rs = rsqrtf(var + 1e-5f);
  #pragma unroll
  for (int j = 0; j < 6; ++j) {
    int c = lane + 64 * j;
    float v = (vals[j] - m) * rs * g[c] + b[c];
    if (FRAGOUT) out[frag_addr(row, c, 12)] = __float2bfloat16(v);
    else         out[(size_t)row * 384 + c] = __float2bfloat16(v);
  }
}

// ---------------- GEMM (r20 measured-best): A row-major LDS-staged, B frag regs ----
// EPI 0: bf16; 2: +resid(f32,scatter)->bf16
template<int EPI, int KTOT>
__global__ __launch_bounds__(256) void gemm_bt(const bf16* __restrict__ A,
    const bf16* __restrict__ Bt, const float* __restrict__ bias,
    bf16* __restrict__ Cb, float* __restrict__ Cf, const float* __restrict__ resid,
    const bf16* __restrict__ residb, int M, int N) {
  constexpr int NKF = KTOT >> 5;
  constexpr int NT  = KTOT >> 5;
  __shared__ bf16 lsA[2][128 * 32];
  const int t = threadIdx.x;
  const int lane = t & 63;
  const int wave = t >> 6;
  const int wm = wave >> 1, wn = wave & 1;
  const int lrow = lane & 15;
  const int lk = (lane >> 4) * 8;
  const int nbx = N >> 7;
  const int nwg = (M >> 7) * nbx;
  const int cpx = nwg >> 3;
  const int id2 = (blockIdx.x & 7) * cpx + (blockIdx.x >> 3);
  const int n0 = (id2 % nbx) * 128;
  const int m0 = (id2 / nbx) * 128;

  f32x4 acc[4][4];
  #pragma unroll
  for (int i = 0; i < 4; ++i)
    #pragma unroll
    for (int j = 0; j < 4; ++j) acc[i][j] = (f32x4){0.f, 0.f, 0.f, 0.f};

  const int e0 = t * 8;
  const int r0 = e0 >> 5, c0s = e0 & 31;
  const bf16* aptr0 = A + (size_t)(m0 + r0) * KTOT + c0s;
  const int e1 = (256 + t) * 8;
  const int r1 = e1 >> 5, c1s = e1 & 31;
  const bf16* aptr1 = A + (size_t)(m0 + r1) * KTOT + c1s;
  const bf16* fb = Bt + (((size_t)((n0 >> 4) + wn * 4) * NKF) * 64 + lane) * 8;

  auto stageA = [&](int buf, int tile) {
    __builtin_amdgcn_global_load_lds(
        (const __attribute__((address_space(1))) void*)(aptr0 + tile * 32),
        (__attribute__((address_space(3))) void*)&lsA[buf][e0], 16, 0, 0);
    __builtin_amdgcn_global_load_lds(
        (const __attribute__((address_space(1))) void*)(aptr1 + tile * 32),
        (__attribute__((address_space(3))) void*)&lsA[buf][e1], 16, 0, 0);
  };

  auto loadB = [&](int kf, short8 (&dst)[4]) {
    const bf16* p = fb + kf * 512;
    #pragma unroll
    for (int ni = 0; ni < 4; ++ni)
      dst[ni] = *(const short8*)(p + (size_t)ni * NKF * 512);
  };

  auto computeA = [&](int buf, const short8 (&bfr)[4]) {
    short8 af[4];
    #pragma unroll
    for (int mi = 0; mi < 4; ++mi)
      af[mi] = *(const short8*)&lsA[buf][(wm * 64 + mi * 16 + lrow) * 32 + lk];
    #pragma unroll
    for (int mi = 0; mi < 4; ++mi)
      #pragma unroll
      for (int ni = 0; ni < 4; ++ni)
        acc[mi][ni] = __builtin_amdgcn_mfma_f32_16x16x32_bf16(af[mi], bfr[ni], acc[mi][ni], 0, 0, 0);
  };

  short8 b0[4], b1[4];
  stageA(0, 0);
  loadB(0, b0);
  __syncthreads();
  #pragma unroll 2
  for (int it = 0; it < NT; it += 2) {
    if (it + 1 < NT) {
      stageA(1, it + 1);
      loadB(it + 1, b1);
    }
    computeA(0, b0);
    __syncthreads();
    if (it + 1 < NT) {
      if (it + 2 < NT) {
        stageA(0, it + 2);
        loadB(it + 2, b0);
      }
      computeA(1, b1);
      __syncthreads();
    }
  }

  #pragma unroll
  for (int mi = 0; mi < 4; ++mi) {
    #pragma unroll
    for (int ni = 0; ni < 4; ++ni) {
      int col = n0 + wn * 64 + ni * 16 + lrow;
      float bv = bias[col];
      #pragma unroll
      for (int j = 0; j < 4; ++j) {
        int row = m0 + wm * 64 + mi * 16 + (lane >> 4) * 4 + j;
        float v = acc[mi][ni][j] + bv;
        if constexpr (EPI == 0) {
          Cb[(size_t)row * N + col] = __float2bfloat16(v);
        } else if constexpr (EPI == 2) {
          int w = row / 49, p = row - w * 49;
          int bb = w >> 6, wy = (w >> 3) & 7, wx = w & 7;
          int iy = p / 7, ix = p - iy * 7;
          int l = (wy * 7 + iy) * 56 + wx * 7 + ix;
          size_t di = ((size_t)bb * LL + l) * 384 + col;
          Cb[di] = __float2bfloat16(v + resid[di]);
        }
      }
    }
  }
}

// ---------------- FUSED MLP: out = gelu(h2@W1+b1)@W2 + b2 + x2 ----------------
// BM=64, 256 thr, 4 waves (wm=wave>>1 row strip of 32, wn=wave&1).
// A-panel (64x384, frag order from LN2) staged ONCE into LDS (linear 48KB copy).
// Per chunk c (12 chunks of 128 mid-cols):
//   phase1: acc1(32x64/wave) = A@W1[:,c]  (12 ksteps, no barriers)
//   bias1+gelu -> scatter to lsM in A-frag order (nkf=4); barrier
//   phase2: acc2(32x192/wave) += lsM @ W2[c,:] (4 ksteps); barrier
// Epilogue: acc2 + b2 + x2b -> f32 out.
__global__ __launch_bounds__(256) void mlp_fused(const bf16* __restrict__ Af,
    const bf16* __restrict__ W1f, const bf16* __restrict__ W2f,
    const float* __restrict__ b1, const float* __restrict__ b2,
    const bf16* __restrict__ residb, float* __restrict__ outp) {
  __shared__ bf16 lsA[64 * 384];   // 48 KB, frag-ordered panel (nkf=12)
  __shared__ bf16 lsM[64 * 128];   // 16 KB, mid chunk, frag-ordered (nkf=4)
  const int t = threadIdx.x;
  const int lane = t & 63;
  const int wave = t >> 6;
  const int wm = wave >> 1, wn = wave & 1;
  const int g = lane >> 4, r15 = lane & 15;
  const int nwg = ROWS / 64;               // 1568, div by 8
  const int cpx = nwg >> 3;
  const int blk = (blockIdx.x & 7) * cpx + (blockIdx.x >> 3);
  const int m0 = blk * 64;

  // linear copy of the frag-ordered A panel (rows m0..m0+64 are contiguous)
  const bf16* srcA = Af + (size_t)(m0 >> 4) * 12 * 512;
  #pragma unroll
  for (int i = 0; i < 12; ++i) {
    int e = (i * 256 + t) * 8;
    __builtin_amdgcn_global_load_lds(
        (const __attribute__((address_space(1))) void*)(srcA + e),
        (__attribute__((address_space(3))) void*)&lsA[e], 16, 0, 0);
  }

  f32x4 acc2[2][12];
  #pragma unroll
  for (int i = 0; i < 2; ++i)
    #pragma unroll
    for (int j = 0; j < 12; ++j) acc2[i][j] = (f32x4){0.f, 0.f, 0.f, 0.f};

  __syncthreads();    // A panel resident (drains vmcnt)

  for (int c = 0; c < 12; ++c) {
    // ---- phase 1: acc1 = A(rows wm*32..+32) @ W1 cols [c*128 + wn*64 .. +64) ----
    f32x4 acc1[2][4];
    #pragma unroll
    for (int i = 0; i < 2; ++i)
      #pragma unroll
      for (int j = 0; j < 4; ++j) acc1[i][j] = (f32x4){0.f, 0.f, 0.f, 0.f};
    const int nfb1 = c * 8 + wn * 4;               // W1 frag col base
    #pragma unroll
    for (int ks = 0; ks < 12; ++ks) {
      short8 af[2];
      #pragma unroll
      for (int mi = 0; mi < 2; ++mi) {
        int rf = wm * 2 + mi;
        af[mi] = *(const short8*)&lsA[((rf * 12 + ks) * 64 + lane) * 8];
      }
      short8 bf1[4];
      #pragma unroll
      for (int ni = 0; ni < 4; ++ni)
        bf1[ni] = *(const short8*)&W1f[(((size_t)(nfb1 + ni) * 12 + ks) * 64 + lane) * 8];
      #pragma unroll
      for (int mi = 0; mi < 2; ++mi)
        #pragma unroll
        for (int ni = 0; ni < 4; ++ni)
          acc1[mi][ni] = __builtin_amdgcn_mfma_f32_16x16x32_bf16(af[mi], bf1[ni], acc1[mi][ni], 0, 0, 0);
    }
    __syncthreads();   // all waves done READING lsM from previous chunk's phase 2
    // ---- bias1 + gelu -> lsM (A-frag order, nkf=4); local row r, local col cc ----
    #pragma unroll
    for (int mi = 0; mi < 2; ++mi)
      #pragma unroll
      for (int ni = 0; ni < 4; ++ni) {
        int ccol = wn * 64 + ni * 16 + r15;
        float bv = b1[c * 128 + ccol];
        #pragma unroll
        for (int j = 0; j < 4; ++j) {
          int r = wm * 32 + mi * 16 + g * 4 + j;
          float v = gelu_fast(acc1[mi][ni][j] + bv);
          size_t ad = ((size_t)(r >> 4) * 4 + (ccol >> 5)) * 512
                    + (size_t)(((r & 15) + (((ccol & 31) >> 3) << 4)) * 8 + (ccol & 7));
          lsM[ad] = __float2bfloat16(v);
        }
      }
    __syncthreads();   // lsM chunk ready
    // ---- phase 2: acc2 += mid(64x128) @ W2[c*128..,:384], wave cols wn*192..+192 ----
    #pragma unroll
    for (int k2 = 0; k2 < 4; ++k2) {
      short8 af2[2];
      #pragma unroll
      for (int mi = 0; mi < 2; ++mi) {
        int rf = wm * 2 + mi;
        af2[mi] = *(const short8*)&lsM[((rf * 4 + k2) * 64 + lane) * 8];
      }
      const int kf2 = c * 4 + k2;
      #pragma unroll
      for (int ni = 0; ni < 12; ++ni) {
        short8 bf2 = *(const short8*)&W2f[(((size_t)(wn * 12 + ni) * 48 + kf2) * 64 + lane) * 8];
        #pragma unroll
        for (int mi = 0; mi < 2; ++mi)
          acc2[mi][ni] = __builtin_amdgcn_mfma_f32_16x16x32_bf16(af2[mi], bf2, acc2[mi][ni], 0, 0, 0);
      }
    }
  }

  // ---- epilogue: + b2 + x2 residual -> f32 out ----
  #pragma unroll
  for (int mi = 0; mi < 2; ++mi)
    #pragma unroll
    for (int ni = 0; ni < 12; ++ni) {
      int col = wn * 192 + ni * 16 + r15;
      float bv = b2[col];
      #pragma unroll
      for (int j = 0; j < 4; ++j) {
        int row = m0 + wm * 32 + mi * 16 + g * 4 + j;
        size_t di = (size_t)row * 384 + col;
        outp[di] = acc2[mi][ni][j] + bv + bf2f(*(const unsigned short*)&residb[di]);
      }
    }
}

// ---------------- MFMA attention: one wave per (window, head) ----------------
__global__ __launch_bounds__(256) void attn_mfma(const bf16* __restrict__ qkv,
    const f32x4* __restrict__ biasM, bf16* __restrict__ out) {
  __shared__ __align__(16) short lds4[4][6272];
  const int wv = threadIdx.x >> 6;
  const int lane = threadIdx.x & 63;
  const int w = blockIdx.x * 4 + wv;
  const int h = blockIdx.y;
  short* L = &lds4[wv][0];
  const short* base = (const short*)(qkv + (size_t)w * 49 * 1152 + h * 32);

  #pragma unroll
  for (int i = 0; i < 4; ++i) {
    int t = i * 64 + lane;
    int r = t >> 2, c = t & 3;
    short8 qv, kv, vv;
    if (r < 49) {
      const short* rp = base + (size_t)r * 1152;
      qv = *(const short8*)(rp + c * 8);
      kv = *(const short8*)(rp + 384 + c * 8);
      vv = *(const short8*)(rp + 768 + c * 8);
    } else {
      qv = (short8)0; kv = (short8)0; vv = (short8)0;
    }
    *(short8*)&L[r * 32 + c * 8] = kv;
    *(short8*)&L[2048 + r * 32 + c * 8] = qv;
    #pragma unroll
    for (int j = 0; j < 8; ++j) L[4096 + (c * 8 + j) * 68 + r] = vv[j];
  }

  const int g = lane >> 4, r15 = lane & 15;

  short8 ka[4], qb[4];
  #pragma unroll
  for (int mi = 0; mi < 4; ++mi)
    ka[mi] = *(const short8*)&L[(mi * 16 + r15) * 32 + g * 8];
  #pragma unroll
  for (int ni = 0; ni < 4; ++ni)
    qb[ni] = *(const short8*)&L[2048 + (ni * 16 + r15) * 32 + g * 8];

  f32x4 sT[4][4];
  #pragma unroll
  for (int mi = 0; mi < 4; ++mi)
    #pragma unroll
    for (int ni = 0; ni < 4; ++ni)
      sT[mi][ni] = biasM[((h * 4 + mi) * 4 + ni) * 64 + lane];
  #pragma unroll
  for (int mi = 0; mi < 4; ++mi)
    #pragma unroll
    for (int ni = 0; ni < 4; ++ni)
      sT[mi][ni] = __builtin_amdgcn_mfma_f32_16x16x32_bf16(ka[mi], qb[ni], sT[mi][ni], 0, 0, 0);

  float inv_[4];
  #pragma unroll
  for (int ni = 0; ni < 4; ++ni) {
    float m = -1e30f;
    #pragma unroll
    for (int mi = 0; mi < 4; ++mi)
      #pragma unroll
      for (int j = 0; j < 4; ++j) m = fmaxf(m, sT[mi][ni][j]);
    m = fmaxf(m, __shfl_xor(m, 16));
    m = fmaxf(m, __shfl_xor(m, 32));
    float s = 0.f;
    #pragma unroll
    for (int mi = 0; mi < 4; ++mi)
      #pragma unroll
      for (int j = 0; j < 4; ++j) {
        float p = __expf(sT[mi][ni][j] - m);
        sT[mi][ni][j] = p; s += p;
      }
    s += __shfl_xor(s, 16);
    s += __shfl_xor(s, 32);
    inv_[ni] = 1.f / s;
  }

  s4 pa[4][4];
  #pragma unroll
  for (int mi = 0; mi < 4; ++mi)
    #pragma unroll
    for (int ni = 0; ni < 4; ++ni) {
      s4 p;
      #pragma unroll
      for (int j = 0; j < 4; ++j)
        p[j] = (short)f2bf_bits(sT[mi][ni][j] * inv_[ni]);
      pa[mi][ni] = p;
    }

  s4 vb[4][2];
  #pragma unroll
  for (int mi = 0; mi < 4; ++mi)
    #pragma unroll
    for (int di = 0; di < 2; ++di)
      vb[mi][di] = *(const s4*)&L[4096 + (di * 16 + r15) * 68 + mi * 16 + g * 4];

  f32x4 o[4][2];
  #pragma unroll
  for (int ni = 0; ni < 4; ++ni)
    #pragma unroll
    for (int di = 0; di < 2; ++di) o[ni][di] = (f32x4){0.f, 0.f, 0.f, 0.f};

  asm volatile("s_nop 3" ::: );
  #pragma unroll
  for (int ni = 0; ni < 4; ++ni)
    #pragma unroll
    for (int di = 0; di < 2; ++di)
      #pragma unroll
      for (int mi = 0; mi < 4; ++mi) {
#if __has_builtin(__builtin_amdgcn_mfma_f32_16x16x16bf16_1k)
        o[ni][di] = __builtin_amdgcn_mfma_f32_16x16x16bf16_1k(pa[mi][ni], vb[mi][di], o[ni][di], 0, 0, 0);
#else
        asm volatile("v_mfma_f32_16x16x16_bf16 %0, %1, %2, %0"
                     : "+v"(o[ni][di]) : "v"(pa[mi][ni]), "v"(vb[mi][di]));
#endif
      }
  asm volatile("s_nop 7\n\ts_nop 7" ::: );

  bf16* op = out + ((size_t)w * 49) * 384 + h * 32;
  #pragma unroll
  for (int ni = 0; ni < 4; ++ni)
    #pragma unroll
    for (int di = 0; di < 2; ++di)
      #pragma unroll
      for (int j = 0; j < 4; ++j) {
        int q = ni * 16 + g * 4 + j;
        if (q < 49)
          op[(size_t)q * 384 + di * 16 + r15] = __float2bfloat16(o[ni][di][j]);
      }
}

// ---------------- launch ----------------
extern "C" void kernel_launch(void* const* d_in, const int* in_sizes, int n_in,
                              void* d_out, int out_size, void* d_ws, size_t ws_size,
                              hipStream_t stream) {
  const float* x      = (const float*)d_in[0];
  const float* ln1_g  = (const float*)d_in[1];
  const float* ln1_b  = (const float*)d_in[2];
  const float* qkv_w  = (const float*)d_in[3];
  const float* qkv_b  = (const float*)d_in[4];
  const float* rpb    = (const float*)d_in[5];
  const float* proj_w = (const float*)d_in[6];
  const float* proj_b = (const float*)d_in[7];
  const float* ln2_g  = (const float*)d_in[8];
  const float* ln2_b  = (const float*)d_in[9];
  const float* mlp_w1 = (const float*)d_in[10];
  const float* mlp_b1 = (const float*)d_in[11];
  const float* mlp_w2 = (const float*)d_in[12];
  const float* mlp_b2 = (const float*)d_in[13];
  const int*   rel    = (const int*)d_in[14];

  char* ws = (char*)d_ws;
  const size_t OFF_WQKV  = 0;
  const size_t OFF_WPROJ = OFF_WQKV + (size_t)1152 * 384 * 2;
  const size_t OFF_WM1   = OFF_WPROJ + (size_t)384 * 384 * 2;
  const size_t OFF_WM2   = OFF_WM1 + (size_t)1536 * 384 * 2;
  const size_t OFF_QB    = OFF_WM2 + (size_t)384 * 1536 * 2;
  const size_t OFF_HWIN  = 3659776;
  const size_t OFF_QKV   = OFF_HWIN + (size_t)ROWS * 384 * 2;
  const size_t OFF_ATTN  = OFF_QKV + (size_t)ROWS * 1152 * 2;
  const size_t OFF_X2    = OFF_ATTN + (size_t)ROWS * 384 * 2;   // bf16
  const size_t OFF_H2    = OFF_HWIN;  // reuse h_win region (frag-ordered now)
  const size_t OFF_BIASM = OFF_X2 + (size_t)ROWS * 384 * 2;

  bf16*  wqkv  = (bf16*)(ws + OFF_WQKV);
  bf16*  wproj = (bf16*)(ws + OFF_WPROJ);
  bf16*  wm1   = (bf16*)(ws + OFF_WM1);
  bf16*  wm2   = (bf16*)(ws + OFF_WM2);
  float* qb    = (float*)(ws + OFF_QB);
  f32x4* biasM = (f32x4*)(ws + OFF_BIASM);
  bf16*  hwin  = (bf16*)(ws + OFF_HWIN);
  bf16*  qkvb  = (bf16*)(ws + OFF_QKV);
  bf16*  attnb = (bf16*)(ws + OFF_ATTN);
  bf16*  x2b   = (bf16*)(ws + OFF_X2);
  bf16*  h2    = (bf16*)(ws + OFF_H2);
  float* outp  = (float*)d_out;

  // prep: weights -> MFMA B-fragment order
  prep_fragB<<<dim3(1152 / 16, 384 / 32), 64, 0, stream>>>(qkv_w, wqkv, 384, 1152, 384, SCALE);
  prep_fragB<<<dim3(384 / 16, 384 / 32), 64, 0, stream>>>(proj_w, wproj, 384, 384, 0, 1.f);
  prep_fragB<<<dim3(1536 / 16, 384 / 32), 64, 0, stream>>>(mlp_w1, wm1, 384, 1536, 0, 1.f);
  prep_fragB<<<dim3(384 / 16, 1536 / 32), 64, 0, stream>>>(mlp_w2, wm2, 1536, 384, 0, 1.f);
  prep_qb<<<5, 256, 0, stream>>>(qkv_b, qb);
  prep_biasM<<<dim3(12, 16), 64, 0, stream>>>(rpb, rel, biasM);

  // 1. LN1 + window partition -> bf16 row-major
  ln_kernel<true, false, false><<<ROWS / 4, 256, 0, stream>>>(x, nullptr, ln1_g, ln1_b, hwin);
  // 2. QKV GEMM  (nwg = 7056)
  gemm_bt<0, 384><<<(1152 / 128) * (ROWS / 128), 256, 0, stream>>>(
      hwin, wqkv, qb, qkvb, nullptr, nullptr, nullptr, ROWS, 1152);
  // 3. windowed attention (MFMA)
  attn_mfma<<<dim3(512, HEADS), 256, 0, stream>>>(qkvb, biasM, attnb);
  // 4. proj GEMM + window-reverse + residual -> x2 (bf16, token order; nwg = 2352)
  gemm_bt<2, 384><<<(384 / 128) * (ROWS / 128), 256, 0, stream>>>(
      attnb, wproj, proj_b, x2b, nullptr, x, nullptr, ROWS, 384);
  // 5. LN2 -> h2 in A-FRAGMENT order (nkf=12)
  ln_kernel<false, true, true><<<ROWS / 4, 256, 0, stream>>>(nullptr, x2b, ln2_g, ln2_b, h2);
  // 6+7. FUSED MLP (nwg = 1568, div by 8)
  mlp_fused<<<ROWS / 64, 256, 0, stream>>>(h2, wm1, wm2, mlp_b1, mlp_b2, x2b, outp);
}

// Round 24
// 930.367 us; speedup vs baseline: 2.4209x; 2.4209x over previous
//
#include <hip/hip_runtime.h>
#include <hip/hip_bf16.h>
#include <cstdint>
#include <cstddef>

#define HEADS 12
#define LL 3136
#define ROWS 100352   // 32*3136
#define SCALE 0.17677669529663687f

typedef __hip_bfloat16 bf16;
typedef __attribute__((ext_vector_type(8))) short short8;
typedef __attribute__((ext_vector_type(4))) short s4;
typedef __attribute__((ext_vector_type(4))) float f32x4;

__device__ __forceinline__ float bf2f(unsigned short u) {
  union { uint32_t u32; float f; } x; x.u32 = ((uint32_t)u) << 16; return x.f;
}
__device__ __forceinline__ unsigned short f2bf_bits(float f) {
  union { float f; uint32_t u; } x; x.f = f;
  uint32_t r = x.u + 0x7fffu + ((x.u >> 16) & 1u);
  return (unsigned short)(r >> 16);
}
// tanh-form GELU via hw exp; max |err| ~3e-4.
__device__ __forceinline__ float gelu_fast(float x) {
  float t2 = x * (1.5957691216f + 0.0713548162726f * x * x);
  float e = __expf(t2);
  return x * (e / (e + 1.0f));
}

// ---------------- prep kernels ----------------
// Pack weight src[K][N] (fp32, row-major) into MFMA B-fragment order.
__global__ __launch_bounds__(64) void prep_fragB(const float* __restrict__ src,
    bf16* __restrict__ dst, int K, int N, int scaleLim, float scale) {
  const int nf = blockIdx.x, kf = blockIdx.y;
  const int l = threadIdx.x;
  const int n = nf * 16 + (l & 15);
  const int k0 = kf * 32 + (l >> 4) * 8;
  const float sc = (n < scaleLim) ? scale : 1.f;
  short8 v;
  #pragma unroll
  for (int j = 0; j < 8; ++j)
    v[j] = (short)f2bf_bits(src[(size_t)(k0 + j) * N + n] * sc);
  *(short8*)&dst[(((size_t)nf * (K >> 5) + kf) * 64 + l) * 8] = v;
}

__global__ void prep_qb(const float* __restrict__ qkv_b, float* __restrict__ qb) {
  int idx = blockIdx.x * 256 + threadIdx.x;
  if (idx < 1152) qb[idx] = qkv_b[idx] * (idx < 384 ? SCALE : 1.0f);
}

// biasM[h][mi][ni][lane] = f32x4 matching the 16x16 MFMA D-layout
__global__ void prep_biasM(const float* __restrict__ rpb, const int* __restrict__ rel,
                           f32x4* __restrict__ biasM) {
  int h = blockIdx.x;
  int t = blockIdx.y;
  int mi = t >> 2, ni = t & 3;
  int lane = threadIdx.x;
  int q = ni * 16 + (lane & 15);
  int g = lane >> 4;
  f32x4 v;
  #pragma unroll
  for (int j = 0; j < 4; ++j) {
    int k = mi * 16 + g * 4 + j;
    float b;
    if (k < 49) b = (q < 49) ? rpb[rel[q * 49 + k] * HEADS + h] : 0.f;
    else        b = -1e30f;
    v[j] = b;
  }
  biasM[((h * 4 + mi) * 4 + ni) * 64 + lane] = v;
}

// ---------------- LayerNorm (+ optional window partition, fp32 or bf16 input) --------
template<bool WIN, bool BF16IN>
__global__ __launch_bounds__(256) void ln_kernel(const float* __restrict__ xf,
    const bf16* __restrict__ xb, const float* __restrict__ g,
    const float* __restrict__ b, bf16* __restrict__ out) {
  int row = blockIdx.x * 4 + (threadIdx.x >> 6);
  int lane = threadIdx.x & 63;
  size_t src;
  if (WIN) {
    int w = row / 49, p = row - w * 49;
    int bb = w >> 6, wy = (w >> 3) & 7, wx = w & 7;
    int iy = p / 7, ix = p - iy * 7;
    int l = (wy * 7 + iy) * 56 + wx * 7 + ix;
    src = ((size_t)bb * LL + l) * 384;
  } else {
    src = (size_t)row * 384;
  }
  float vals[6];
  float s = 0.f, s2 = 0.f;
  #pragma unroll
  for (int j = 0; j < 6; ++j) {
    float v = BF16IN ? bf2f(*(const unsigned short*)&xb[src + lane + 64 * j])
                     : xf[src + lane + 64 * j];
    vals[j] = v; s += v; s2 += v * v;
  }
  #pragma unroll
  for (int off = 32; off >= 1; off >>= 1) {
    s  += __shfl_xor(s, off);
    s2 += __shfl_xor(s2, off);
  }
  float m  = s * (1.f / 384.f);
  float var = s2 * (1.f / 384.f) - m * m;
  float rs = rsqrtf(var + 1e-5f);
  bf16* orow = out + (size_t)row * 384;
  #pragma unroll
  for (int j = 0; j < 6; ++j) {
    int c = lane + 64 * j;
    orow[c] = __float2bfloat16((vals[j] - m) * rs * g[c] + b[c]);
  }
}

// ---------------- GEMM: C[M][N] = A[M][K] (bf16) * Bfrag + bias ----------------
// Measured-best structure (r20): template K (compile-time strides, pointer-bump
// addressing), 2-buffer A staging via global_load_lds (lane-linear 16B/lane),
// B fragment-packed in registers, manual 2-iter unroll with NAMED b0/b1 (no
// register copies), one __syncthreads per K-step, XCD-swizzled 1-D grid.
// EPI 0: bf16; 1: fastGELU->bf16; 2: +resid(f32,scatter)->bf16; 3: +residb(bf16)->f32
template<int EPI, int KTOT>
__global__ __launch_bounds__(256) void gemm_bt(const bf16* __restrict__ A,
    const bf16* __restrict__ Bt, const float* __restrict__ bias,
    bf16* __restrict__ Cb, float* __restrict__ Cf, const float* __restrict__ resid,
    const bf16* __restrict__ residb, int M, int N) {
  constexpr int NKF = KTOT >> 5;
  constexpr int NT  = KTOT >> 5;
  __shared__ bf16 lsA[2][128 * 32];
  const int t = threadIdx.x;
  const int lane = t & 63;
  const int wave = t >> 6;
  const int wm = wave >> 1, wn = wave & 1;
  const int lrow = lane & 15;
  const int lk = (lane >> 4) * 8;
  const int nbx = N >> 7;
  const int nwg = (M >> 7) * nbx;
  const int cpx = nwg >> 3;
  const int id2 = (blockIdx.x & 7) * cpx + (blockIdx.x >> 3);
  const int n0 = (id2 % nbx) * 128;
  const int m0 = (id2 / nbx) * 128;

  f32x4 acc[4][4];
  #pragma unroll
  for (int i = 0; i < 4; ++i)
    #pragma unroll
    for (int j = 0; j < 4; ++j) acc[i][j] = (f32x4){0.f, 0.f, 0.f, 0.f};

  // incremental pointers (compile-time strides; bumped per K-step)
  const int e0 = t * 8;                 // first staged element (of 2 per thread)
  const int r0 = e0 >> 5, c0s = e0 & 31;
  const bf16* aptr0 = A + (size_t)(m0 + r0) * KTOT + c0s;
  const int e1 = (256 + t) * 8;
  const int r1 = e1 >> 5, c1s = e1 & 31;
  const bf16* aptr1 = A + (size_t)(m0 + r1) * KTOT + c1s;
  const bf16* fb = Bt + (((size_t)((n0 >> 4) + wn * 4) * NKF) * 64 + lane) * 8;

  auto stageA = [&](int buf, int tile) {
    __builtin_amdgcn_global_load_lds(
        (const __attribute__((address_space(1))) void*)(aptr0 + tile * 32),
        (__attribute__((address_space(3))) void*)&lsA[buf][e0], 16, 0, 0);
    __builtin_amdgcn_global_load_lds(
        (const __attribute__((address_space(1))) void*)(aptr1 + tile * 32),
        (__attribute__((address_space(3))) void*)&lsA[buf][e1], 16, 0, 0);
  };

  auto loadB = [&](int kf, short8 (&dst)[4]) {
    const bf16* p = fb + kf * 512;
    #pragma unroll
    for (int ni = 0; ni < 4; ++ni)
      dst[ni] = *(const short8*)(p + (size_t)ni * NKF * 512);
  };

  auto computeA = [&](int buf, const short8 (&bfr)[4]) {
    short8 af[4];
    #pragma unroll
    for (int mi = 0; mi < 4; ++mi)
      af[mi] = *(const short8*)&lsA[buf][(wm * 64 + mi * 16 + lrow) * 32 + lk];
    #pragma unroll
    for (int mi = 0; mi < 4; ++mi)
      #pragma unroll
      for (int ni = 0; ni < 4; ++ni)
        acc[mi][ni] = __builtin_amdgcn_mfma_f32_16x16x32_bf16(af[mi], bfr[ni], acc[mi][ni], 0, 0, 0);
  };

  short8 b0[4], b1[4];
  stageA(0, 0);
  loadB(0, b0);
  __syncthreads();                 // buf0 ready
  // manual 2-iter unroll: even iter uses buf0/b0, odd uses buf1/b1 — no copies.
  #pragma unroll 2
  for (int it = 0; it < NT; it += 2) {
    // even iteration
    if (it + 1 < NT) {
      stageA(1, it + 1);
      loadB(it + 1, b1);
    }
    computeA(0, b0);
    __syncthreads();
    // odd iteration
    if (it + 1 < NT) {
      if (it + 2 < NT) {
        stageA(0, it + 2);
        loadB(it + 2, b0);
      }
      computeA(1, b1);
      __syncthreads();
    }
  }

  #pragma unroll
  for (int mi = 0; mi < 4; ++mi) {
    #pragma unroll
    for (int ni = 0; ni < 4; ++ni) {
      int col = n0 + wn * 64 + ni * 16 + lrow;
      float bv = bias[col];
      #pragma unroll
      for (int j = 0; j < 4; ++j) {
        int row = m0 + wm * 64 + mi * 16 + (lane >> 4) * 4 + j;
        float v = acc[mi][ni][j] + bv;
        if constexpr (EPI == 0) {
          Cb[(size_t)row * N + col] = __float2bfloat16(v);
        } else if constexpr (EPI == 1) {
          Cb[(size_t)row * N + col] = __float2bfloat16(gelu_fast(v));
        } else if constexpr (EPI == 2) {
          int w = row / 49, p = row - w * 49;
          int bb = w >> 6, wy = (w >> 3) & 7, wx = w & 7;
          int iy = p / 7, ix = p - iy * 7;
          int l = (wy * 7 + iy) * 56 + wx * 7 + ix;
          size_t di = ((size_t)bb * LL + l) * 384 + col;
          Cb[di] = __float2bfloat16(v + resid[di]);
        } else {
          size_t di = (size_t)row * N + col;
          Cf[di] = v + bf2f(*(const unsigned short*)&residb[di]);
        }
      }
    }
  }
}

// ---------------- MFMA attention: one wave per (window, head) ----------------
__global__ __launch_bounds__(256) void attn_mfma(const bf16* __restrict__ qkv,
    const f32x4* __restrict__ biasM, bf16* __restrict__ out) {
  __shared__ __align__(16) short lds4[4][6272];
  const int wv = threadIdx.x >> 6;
  const int lane = threadIdx.x & 63;
  const int w = blockIdx.x * 4 + wv;
  const int h = blockIdx.y;
  short* L = &lds4[wv][0];
  const short* base = (const short*)(qkv + (size_t)w * 49 * 1152 + h * 32);

  #pragma unroll
  for (int i = 0; i < 4; ++i) {
    int t = i * 64 + lane;
    int r = t >> 2, c = t & 3;
    short8 qv, kv, vv;
    if (r < 49) {
      const short* rp = base + (size_t)r * 1152;
      qv = *(const short8*)(rp + c * 8);
      kv = *(const short8*)(rp + 384 + c * 8);
      vv = *(const short8*)(rp + 768 + c * 8);
    } else {
      qv = (short8)0; kv = (short8)0; vv = (short8)0;
    }
    *(short8*)&L[r * 32 + c * 8] = kv;
    *(short8*)&L[2048 + r * 32 + c * 8] = qv;
    #pragma unroll
    for (int j = 0; j < 8; ++j) L[4096 + (c * 8 + j) * 68 + r] = vv[j];
  }

  const int g = lane >> 4, r15 = lane & 15;

  short8 ka[4], qb[4];
  #pragma unroll
  for (int mi = 0; mi < 4; ++mi)
    ka[mi] = *(const short8*)&L[(mi * 16 + r15) * 32 + g * 8];
  #pragma unroll
  for (int ni = 0; ni < 4; ++ni)
    qb[ni] = *(const short8*)&L[2048 + (ni * 16 + r15) * 32 + g * 8];

  f32x4 sT[4][4];
  #pragma unroll
  for (int mi = 0; mi < 4; ++mi)
    #pragma unroll
    for (int ni = 0; ni < 4; ++ni)
      sT[mi][ni] = biasM[((h * 4 + mi) * 4 + ni) * 64 + lane];
  #pragma unroll
  for (int mi = 0; mi < 4; ++mi)
    #pragma unroll
    for (int ni = 0; ni < 4; ++ni)
      sT[mi][ni] = __builtin_amdgcn_mfma_f32_16x16x32_bf16(ka[mi], qb[ni], sT[mi][ni], 0, 0, 0);

  float inv_[4];
  #pragma unroll
  for (int ni = 0; ni < 4; ++ni) {
    float m = -1e30f;
    #pragma unroll
    for (int mi = 0; mi < 4; ++mi)
      #pragma unroll
      for (int j = 0; j < 4; ++j) m = fmaxf(m, sT[mi][ni][j]);
    m = fmaxf(m, __shfl_xor(m, 16));
    m = fmaxf(m, __shfl_xor(m, 32));
    float s = 0.f;
    #pragma unroll
    for (int mi = 0; mi < 4; ++mi)
      #pragma unroll
      for (int j = 0; j < 4; ++j) {
        float p = __expf(sT[mi][ni][j] - m);
        sT[mi][ni][j] = p; s += p;
      }
    s += __shfl_xor(s, 16);
    s += __shfl_xor(s, 32);
    inv_[ni] = 1.f / s;
  }

  s4 pa[4][4];
  #pragma unroll
  for (int mi = 0; mi < 4; ++mi)
    #pragma unroll
    for (int ni = 0; ni < 4; ++ni) {
      s4 p;
      #pragma unroll
      for (int j = 0; j < 4; ++j)
        p[j] = (short)f2bf_bits(sT[mi][ni][j] * inv_[ni]);
      pa[mi][ni] = p;
    }

  s4 vb[4][2];
  #pragma unroll
  for (int mi = 0; mi < 4; ++mi)
    #pragma unroll
    for (int di = 0; di < 2; ++di)
      vb[mi][di] = *(const s4*)&L[4096 + (di * 16 + r15) * 68 + mi * 16 + g * 4];

  f32x4 o[4][2];
  #pragma unroll
  for (int ni = 0; ni < 4; ++ni)
    #pragma unroll
    for (int di = 0; di < 2; ++di) o[ni][di] = (f32x4){0.f, 0.f, 0.f, 0.f};

  asm volatile("s_nop 3" ::: );
  #pragma unroll
  for (int ni = 0; ni < 4; ++ni)
    #pragma unroll
    for (int di = 0; di < 2; ++di)
      #pragma unroll
      for (int mi = 0; mi < 4; ++mi) {
#if __has_builtin(__builtin_amdgcn_mfma_f32_16x16x16bf16_1k)
        o[ni][di] = __builtin_amdgcn_mfma_f32_16x16x16bf16_1k(pa[mi][ni], vb[mi][di], o[ni][di], 0, 0, 0);
#else
        asm volatile("v_mfma_f32_16x16x16_bf16 %0, %1, %2, %0"
                     : "+v"(o[ni][di]) : "v"(pa[mi][ni]), "v"(vb[mi][di]));
#endif
      }
  asm volatile("s_nop 7\n\ts_nop 7" ::: );

  bf16* op = out + ((size_t)w * 49) * 384 + h * 32;
  #pragma unroll
  for (int ni = 0; ni < 4; ++ni)
    #pragma unroll
    for (int di = 0; di < 2; ++di)
      #pragma unroll
      for (int j = 0; j < 4; ++j) {
        int q = ni * 16 + g * 4 + j;
        if (q < 49)
          op[(size_t)q * 384 + di * 16 + r15] = __float2bfloat16(o[ni][di][j]);
      }
}

// ---------------- launch ----------------
extern "C" void kernel_launch(void* const* d_in, const int* in_sizes, int n_in,
                              void* d_out, int out_size, void* d_ws, size_t ws_size,
                              hipStream_t stream) {
  const float* x      = (const float*)d_in[0];
  const float* ln1_g  = (const float*)d_in[1];
  const float* ln1_b  = (const float*)d_in[2];
  const float* qkv_w  = (const float*)d_in[3];
  const float* qkv_b  = (const float*)d_in[4];
  const float* rpb    = (const float*)d_in[5];
  const float* proj_w = (const float*)d_in[6];
  const float* proj_b = (const float*)d_in[7];
  const float* ln2_g  = (const float*)d_in[8];
  const float* ln2_b  = (const float*)d_in[9];
  const float* mlp_w1 = (const float*)d_in[10];
  const float* mlp_b1 = (const float*)d_in[11];
  const float* mlp_w2 = (const float*)d_in[12];
  const float* mlp_b2 = (const float*)d_in[13];
  const int*   rel    = (const int*)d_in[14];

  char* ws = (char*)d_ws;
  const size_t OFF_WQKV  = 0;
  const size_t OFF_WPROJ = OFF_WQKV + (size_t)1152 * 384 * 2;
  const size_t OFF_WM1   = OFF_WPROJ + (size_t)384 * 384 * 2;
  const size_t OFF_WM2   = OFF_WM1 + (size_t)1536 * 384 * 2;
  const size_t OFF_QB    = OFF_WM2 + (size_t)384 * 1536 * 2;
  const size_t OFF_HWIN  = 3659776;
  const size_t OFF_QKV   = OFF_HWIN + (size_t)ROWS * 384 * 2;
  const size_t OFF_ATTN  = OFF_QKV + (size_t)ROWS * 1152 * 2;
  const size_t OFF_X2    = OFF_ATTN + (size_t)ROWS * 384 * 2;   // bf16
  const size_t OFF_M1    = OFF_QKV;   // reuse qkv+attn regions (dead by then)
  const size_t OFF_H2    = OFF_HWIN;  // reuse h_win region
  const size_t OFF_BIASM = OFF_X2 + (size_t)ROWS * 384 * 2;

  bf16*  wqkv  = (bf16*)(ws + OFF_WQKV);
  bf16*  wproj = (bf16*)(ws + OFF_WPROJ);
  bf16*  wm1   = (bf16*)(ws + OFF_WM1);
  bf16*  wm2   = (bf16*)(ws + OFF_WM2);
  float* qb    = (float*)(ws + OFF_QB);
  f32x4* biasM = (f32x4*)(ws + OFF_BIASM);
  bf16*  hwin  = (bf16*)(ws + OFF_HWIN);
  bf16*  qkvb  = (bf16*)(ws + OFF_QKV);
  bf16*  attnb = (bf16*)(ws + OFF_ATTN);
  bf16*  x2b   = (bf16*)(ws + OFF_X2);
  bf16*  m1    = (bf16*)(ws + OFF_M1);
  bf16*  h2    = (bf16*)(ws + OFF_H2);
  float* outp  = (float*)d_out;

  // prep: weights -> MFMA B-fragment order (grid = (N/16, K/32), 64 thr)
  prep_fragB<<<dim3(1152 / 16, 384 / 32), 64, 0, stream>>>(qkv_w, wqkv, 384, 1152, 384, SCALE);
  prep_fragB<<<dim3(384 / 16, 384 / 32), 64, 0, stream>>>(proj_w, wproj, 384, 384, 0, 1.f);
  prep_fragB<<<dim3(1536 / 16, 384 / 32), 64, 0, stream>>>(mlp_w1, wm1, 384, 1536, 0, 1.f);
  prep_fragB<<<dim3(384 / 16, 1536 / 32), 64, 0, stream>>>(mlp_w2, wm2, 1536, 384, 0, 1.f);
  prep_qb<<<5, 256, 0, stream>>>(qkv_b, qb);
  prep_biasM<<<dim3(12, 16), 64, 0, stream>>>(rpb, rel, biasM);

  // 1. LN1 + window partition -> bf16
  ln_kernel<true, false><<<ROWS / 4, 256, 0, stream>>>(x, nullptr, ln1_g, ln1_b, hwin);
  // 2. QKV GEMM  (nwg = 7056)
  gemm_bt<0, 384><<<(1152 / 128) * (ROWS / 128), 256, 0, stream>>>(
      hwin, wqkv, qb, qkvb, nullptr, nullptr, nullptr, ROWS, 1152);
  // 3. windowed attention (MFMA)
  attn_mfma<<<dim3(512, HEADS), 256, 0, stream>>>(qkvb, biasM, attnb);
  // 4. proj GEMM + window-reverse + residual -> x2 (bf16, token order; nwg = 2352)
  gemm_bt<2, 384><<<(384 / 128) * (ROWS / 128), 256, 0, stream>>>(
      attnb, wproj, proj_b, x2b, nullptr, x, nullptr, ROWS, 384);
  // 5. LN2 (bf16 input)
  ln_kernel<false, true><<<ROWS / 4, 256, 0, stream>>>(nullptr, x2b, ln2_g, ln2_b, h2);
  // 6. MLP1 + fast GELU (nwg = 9408)
  gemm_bt<1, 384><<<(1536 / 128) * (ROWS / 128), 256, 0, stream>>>(
      h2, wm1, mlp_b1, m1, nullptr, nullptr, nullptr, ROWS, 1536);
  // 7. MLP2 + residual(bf16) -> out (nwg = 2352)
  gemm_bt<3, 1536><<<(384 / 128) * (ROWS / 128), 256, 0, stream>>>(
      m1, wm2, mlp_b2, nullptr, outp, nullptr, x2b, ROWS, 384);
}